// Round 2
// baseline (179.063 us; speedup 1.0000x reference)
//
#include <hip/hip_runtime.h>
#include <hip/hip_bf16.h>
#include <math.h>

// DiscretisedBNF loss, MI355X gfx950.
// Pipeline: rowconst -> prep(A1 bf16) -> GEMM1(splitK=8) -> reduce1(bias+t*W1row+leaky->h bf16)
//           -> GEMM2(splitK=8) -> loss (reduce partials + windowed erf-sum + weighted MSE).
// Abel summation (R1 fix: keep the non-saturated k=127 edge term):
//   pO = (125/256)(1+erf(z_127)) - 126/128 - (1/128) sum_{k=1..126} erf(z_k),
//   z_k = (k/64 - 1 - mu_x) / (sigma*sqrt(2)).

typedef __bf16 bf16_t;
typedef __bf16 bf16x8 __attribute__((ext_vector_type(8)));
typedef __bf16 bf16x4 __attribute__((ext_vector_type(4)));
typedef float  f32x4  __attribute__((ext_vector_type(4)));

#define LDK 40  // LDS row stride in bf16 (32 + 8 pad): 80B rows, 16B-aligned, conflict-free b128

__global__ __launch_bounds__(256, 2)
void rowconst_k(const float* __restrict__ t, float4* __restrict__ rc4, float* __restrict__ rt) {
  int i = threadIdx.x;
  float tv = t[i];
  const float L2S = -5.6438561897747248f;  // log2(0.02)
  float p = exp2f(2.0f * tv * L2S);        // 1-gamma = 0.02^(2t)
  float gamma = 1.0f - p;
  float r = sqrtf(p / gamma);
  float w = 1.0f / p;                      // SIGMA1^(-2t)
  rc4[i] = make_float4(gamma, p, r, w);
  rt[i] = tv;
}

__global__ __launch_bounds__(256, 2)
void prep_k(const float* __restrict__ x, const float* __restrict__ noise,
            const float4* __restrict__ rc4, bf16_t* __restrict__ A1) {
  int e = (blockIdx.x * 256 + threadIdx.x) * 4;
  int b = e >> 10;
  float4 rc = rc4[b];
  float4 xv = *(const float4*)(x + e);
  float4 nv = *(const float4*)(noise + e);
  float g = rc.x, gom = rc.x * rc.y;       // gamma, gamma*(1-gamma)
  bf16x4 o;
  o[0] = (__bf16)(g * xv.x + gom * nv.x);
  o[1] = (__bf16)(g * xv.y + gom * nv.y);
  o[2] = (__bf16)(g * xv.z + gom * nv.z);
  o[3] = (__bf16)(g * xv.w + gom * nv.w);
  *(bf16x4*)(A1 + e) = o;
}

// C_partial[blockIdx.z] = A[256 x K, bf16] chunk @ W[K x N, f32->bf16]
// BM=256 (all M), BN=64, BK=32. 4 waves, each 64(m)x64(n) = 4x4 frags of 16x16x32.
__global__ __launch_bounds__(256, 2)
void gemm_k(const bf16_t* __restrict__ A, int lda,
            const float* __restrict__ W, int N,
            float* __restrict__ P, int Ktiles, int Kchunk) {
  __shared__ bf16_t As[256 * LDK];
  __shared__ bf16_t Bs[64 * LDK];
  int tid = threadIdx.x;
  int lane = tid & 63, wave = tid >> 6;
  int n0 = blockIdx.x * 64;
  int k0 = blockIdx.z * Kchunk;
  int bn = tid & 63, bkg = tid >> 6;   // B staging: n, k-group(8)
  int fm = lane & 15, kq = lane >> 4;  // fragment lane decode

  f32x4 acc[4][4];
#pragma unroll
  for (int i = 0; i < 4; ++i)
#pragma unroll
    for (int j = 0; j < 4; ++j) acc[i][j] = (f32x4)0.0f;

  for (int kt = 0; kt < Ktiles; ++kt) {
    int kb = k0 + kt * 32;
    // stage A: thread = row, 4 x 16B
    const bf16_t* Ar = A + (size_t)tid * lda + kb;
#pragma unroll
    for (int j = 0; j < 4; ++j) {
      bf16x8 v = *(const bf16x8*)(Ar + j * 8);
      *(bf16x8*)(&As[tid * LDK + j * 8]) = v;
    }
    // stage B transposed: Bs[n][k], fp32 -> bf16 during load
    {
      const float* Wp = W + (size_t)(kb + bkg * 8) * N + n0 + bn;
      bf16x8 bv;
#pragma unroll
      for (int j = 0; j < 8; ++j) bv[j] = (__bf16)Wp[(size_t)j * N];
      *(bf16x8*)(&Bs[bn * LDK + bkg * 8]) = bv;
    }
    __syncthreads();
    bf16x8 aF[4], bF[4];
#pragma unroll
    for (int i = 0; i < 4; ++i)
      aF[i] = *(const bf16x8*)(&As[(wave * 64 + i * 16 + fm) * LDK + kq * 8]);
#pragma unroll
    for (int j = 0; j < 4; ++j)
      bF[j] = *(const bf16x8*)(&Bs[(j * 16 + fm) * LDK + kq * 8]);
#pragma unroll
    for (int i = 0; i < 4; ++i)
#pragma unroll
      for (int j = 0; j < 4; ++j)
        acc[i][j] = __builtin_amdgcn_mfma_f32_16x16x32_bf16(aF[i], bF[j], acc[i][j], 0, 0, 0);
    __syncthreads();
  }
  // epilogue: C/D layout col=lane&15, row=(lane>>4)*4+reg  [m89-verified]
  float* Pp = P + (size_t)blockIdx.z * 256 * N + n0;
#pragma unroll
  for (int i = 0; i < 4; ++i) {
    int mrow = wave * 64 + i * 16 + kq * 4;
#pragma unroll
    for (int j = 0; j < 4; ++j)
#pragma unroll
      for (int r = 0; r < 4; ++r)
        Pp[(size_t)(mrow + r) * N + j * 16 + fm] = acc[i][j][r];
  }
}

// h = leaky(sum_s P1[s] + t*W1[1024,:] + b1), stored bf16
__global__ __launch_bounds__(256, 2)
void reduce1_k(const float* __restrict__ P1, const float* __restrict__ W1,
               const float* __restrict__ b1, const float* __restrict__ rt,
               bf16_t* __restrict__ h) {
  int e = (blockIdx.x * 256 + threadIdx.x) * 4;
  int b = e >> 11, n = e & 2047;
  float4 s = *(const float4*)(P1 + e);
#pragma unroll
  for (int sp = 1; sp < 8; ++sp) {
    float4 v = *(const float4*)(P1 + (size_t)sp * 524288 + e);
    s.x += v.x; s.y += v.y; s.z += v.z; s.w += v.w;
  }
  float tv = rt[b];
  float4 wl = *(const float4*)(W1 + 1024 * 2048 + n);
  float4 bb = *(const float4*)(b1 + n);
  s.x += tv * wl.x + bb.x;
  s.y += tv * wl.y + bb.y;
  s.z += tv * wl.z + bb.z;
  s.w += tv * wl.w + bb.w;
  bf16x4 o;
  o[0] = (__bf16)(s.x >= 0.f ? s.x : 0.01f * s.x);
  o[1] = (__bf16)(s.y >= 0.f ? s.y : 0.01f * s.y);
  o[2] = (__bf16)(s.z >= 0.f ? s.z : 0.01f * s.z);
  o[3] = (__bf16)(s.w >= 0.f ? s.w : 0.01f * s.w);
  *(bf16x4*)(h + e) = o;
}

// one block per row b; reduce GEMM2 partials, windowed erf bucket sum, weighted MSE
__global__ __launch_bounds__(256, 2)
void loss_k(const float* __restrict__ x, const float* __restrict__ noise,
            const float* __restrict__ P2, const float* __restrict__ b2,
            const float4* __restrict__ rc4, const float* __restrict__ rt,
            float* __restrict__ out) {
  int b = blockIdx.x;
  int tid = threadIdx.x;
  int d = tid * 4;
  float4 rc = rc4[b];
  float tv = rt[b];
  float om = rc.y, r = rc.z, w = rc.w;
  bool lowt = tv < 1e-10f;
  int base2 = b * 2048 + d;
  float me[4] = {0, 0, 0, 0}, lg[4] = {0, 0, 0, 0};
#pragma unroll
  for (int sp = 0; sp < 8; ++sp) {
    float4 v1 = *(const float4*)(P2 + (size_t)sp * 524288 + base2);
    float4 v2 = *(const float4*)(P2 + (size_t)sp * 524288 + base2 + 1024);
    me[0] += v1.x; me[1] += v1.y; me[2] += v1.z; me[3] += v1.w;
    lg[0] += v2.x; lg[1] += v2.y; lg[2] += v2.z; lg[3] += v2.w;
  }
  {
    float4 bb1 = *(const float4*)(b2 + d);
    float4 bb2 = *(const float4*)(b2 + 1024 + d);
    me[0] += bb1.x; me[1] += bb1.y; me[2] += bb1.z; me[3] += bb1.w;
    lg[0] += bb2.x; lg[1] += bb2.y; lg[2] += bb2.z; lg[3] += bb2.w;
  }
  float4 xv = *(const float4*)(x + b * 1024 + d);
  float4 nv = *(const float4*)(noise + b * 1024 + d);
  float xs[4] = {xv.x, xv.y, xv.z, xv.w};
  float ns[4] = {nv.x, nv.y, nv.z, nv.w};
  float accv = 0.f;
#pragma unroll
  for (int c = 0; c < 4; ++c) {
    float mu_x = xs[c] + om * ns[c] - r * me[c];  // mu/gamma - r*mu_eps
    float sig = r * __expf(lg[c]);
    if (lowt) { mu_x = 0.f; sig = 1.f; }
    float invs = 0.70710678118654752f / sig;     // 1/(sigma*sqrt(2))
    float a = invs * 0.015625f;                  // z step per k
    float c0 = (1.f + mu_x) * invs;              // z_k = a*k - c0
    // window |z|<4 for the k=1..126 interior sum: saturated tails counted exactly
    float m64 = 64.f * (1.f + mu_x);
    float wdt = 362.03867196751236f * sig;       // 4/a = 256*sqrt(2)*sig
    float lo = m64 - wdt, hi = m64 + wdt;
    int klo = (lo < 1.f) ? 1 : ((lo > 126.f) ? 127 : (int)ceilf(lo));
    int khi = (hi < 1.f) ? 0 : ((hi > 126.f) ? 126 : (int)floorf(hi));
    float ss = (float)(126 - khi) - (float)(klo - 1);  // erf=+1 above window, -1 below
    for (int k = klo; k <= khi; ++k) ss += erff(fmaf(a, (float)k, -c0));
    // R1 fix: non-saturated right edge term at k=127 (kr_127 = 63/64 < 1, not clamped)
    float z127 = fmaf(a, 127.f, -c0);
    float pO = fmaf(0.48828125f, 1.f + erff(z127),       // (125/256)(1+erf(z127))
                    fmaf(-0.0078125f, ss, -0.984375f));  // -(1/128)ss - 126/128
    float df = xs[c] - pO;
    accv = fmaf(df, df, accv);
  }
  accv *= w;
#pragma unroll
  for (int off = 32; off > 0; off >>= 1) accv += __shfl_down(accv, off, 64);
  __shared__ float red[4];
  if ((tid & 63) == 0) red[tid >> 6] = accv;
  __syncthreads();
  if (tid == 0) {
    const float SCALE = 3.9120230054281461f / 262144.0f;  // -ln(0.02)/(B*D)
    atomicAdd(out, (red[0] + red[1] + red[2] + red[3]) * SCALE);
  }
}

extern "C" void kernel_launch(void* const* d_in, const int* in_sizes, int n_in,
                              void* d_out, int out_size, void* d_ws, size_t ws_size,
                              hipStream_t stream) {
  const float* x     = (const float*)d_in[0];
  const float* t     = (const float*)d_in[1];
  const float* noise = (const float*)d_in[2];
  const float* W1    = (const float*)d_in[3];
  const float* b1    = (const float*)d_in[4];
  const float* W2    = (const float*)d_in[5];
  const float* b2    = (const float*)d_in[6];
  float* out = (float*)d_out;

  // ws layout (needs ~33.6 MB)
  char* ws = (char*)d_ws;
  float4* rc4 = (float4*)ws;                           // 4 KB
  float*  rt  = (float*)(ws + 4096);                   // 1 KB
  bf16_t* A1  = (bf16_t*)(ws + 8192);                  // 512 KB
  bf16_t* h   = (bf16_t*)(ws + 8192 + 524288);         // 1 MB
  float*  P1  = (float*)(ws + 8192 + 524288 + 1048576);            // 16 MB
  float*  P2  = (float*)(ws + 8192 + 524288 + 1048576 + 16777216); // 16 MB

  hipMemsetAsync(d_out, 0, sizeof(float), stream);
  rowconst_k<<<1, 256, 0, stream>>>(t, rc4, rt);
  prep_k<<<256, 256, 0, stream>>>(x, noise, rc4, A1);
  gemm_k<<<dim3(32, 1, 8), 256, 0, stream>>>(A1, 1024, W1, 2048, P1, 4, 128);
  reduce1_k<<<512, 256, 0, stream>>>(P1, W1, b1, rt, h);
  gemm_k<<<dim3(32, 1, 8), 256, 0, stream>>>(h, 2048, W2, 2048, P2, 8, 256);
  loss_k<<<256, 256, 0, stream>>>(x, noise, P2, b2, rc4, rt, out);
}

// Round 3
// 132.004 us; speedup vs baseline: 1.3565x; 1.3565x over previous
//
#include <hip/hip_runtime.h>
#include <hip/hip_bf16.h>
#include <math.h>

// DiscretisedBNF loss, MI355X gfx950.
// Pipeline: prep(row consts + A1 bf16) -> GEMM1(splitK=8) -> reduce1(bias+t*W1row+leaky->h bf16)
//           -> GEMM2(splitK=8) -> loss (reduce partials + windowed erf-sum + weighted MSE).
// Abel summation (k=127 edge kept un-saturated — R1 fix):
//   pO = (125/256)(1+erf(z_127)) - 126/128 - (1/128) sum_{k=1..126} erf(z_k),
//   z_k = (k/64 - 1 - mu_x) / (sigma*sqrt(2)).
// R2: loss_k re-parallelized 1 elem/thread (256->1024 blocks; was 9% occupancy, 34% VALUBusy),
//     branch-free A&S erf replaces ocml erff (divergent-branch serialization).

typedef __bf16 bf16_t;
typedef __bf16 bf16x8 __attribute__((ext_vector_type(8)));
typedef __bf16 bf16x4 __attribute__((ext_vector_type(4)));
typedef float  f32x4  __attribute__((ext_vector_type(4)));

#define LDK 40  // LDS row stride in bf16 (32 + 8 pad): 80B rows, 16B-aligned, conflict-free b128

// Abramowitz-Stegun 7.1.26, |abs err| <= 1.5e-7, branch-free full-range.
__device__ __forceinline__ float erf_f(float x) {
  float ax = __builtin_fabsf(x);
  float t = __builtin_amdgcn_rcpf(fmaf(0.3275911f, ax, 1.0f));
  float p = fmaf(fmaf(fmaf(fmaf(1.061405429f, t, -1.453152027f), t, 1.421413741f),
                      t, -0.284496736f), t, 0.254829592f);
  p *= t;
  float e = __expf(-ax * ax);
  float r = fmaf(-p, e, 1.0f);
  return __builtin_copysignf(r, x);
}

// block b handles row b (1024 elems, 256 thr x 4); also emits row constants.
__global__ __launch_bounds__(256, 2)
void prep_k(const float* __restrict__ x, const float* __restrict__ noise,
            const float* __restrict__ t, float4* __restrict__ rc4,
            float* __restrict__ rt, bf16_t* __restrict__ A1) {
  int b = blockIdx.x;
  float tv = t[b];
  const float L2S = -5.6438561897747248f;  // log2(0.02)
  float p = exp2f(2.0f * tv * L2S);        // 1-gamma = 0.02^(2t)
  float gamma = 1.0f - p;
  if (threadIdx.x == 0) {
    float r = sqrtf(p / gamma);
    float w = 1.0f / p;                    // SIGMA1^(-2t)
    rc4[b] = make_float4(gamma, p, r, w);
    rt[b] = tv;
  }
  int e = (b * 256 + threadIdx.x) * 4;
  float4 xv = *(const float4*)(x + e);
  float4 nv = *(const float4*)(noise + e);
  float g = gamma, gom = gamma * p;        // gamma, gamma*(1-gamma)
  bf16x4 o;
  o[0] = (__bf16)(g * xv.x + gom * nv.x);
  o[1] = (__bf16)(g * xv.y + gom * nv.y);
  o[2] = (__bf16)(g * xv.z + gom * nv.z);
  o[3] = (__bf16)(g * xv.w + gom * nv.w);
  *(bf16x4*)(A1 + e) = o;
}

// C_partial[blockIdx.z] = A[256 x K, bf16] chunk @ W[K x N, f32->bf16]
// BM=256 (all M), BN=64, BK=32. 4 waves, each 64(m)x64(n) = 4x4 frags of 16x16x32.
__global__ __launch_bounds__(256, 2)
void gemm_k(const bf16_t* __restrict__ A, int lda,
            const float* __restrict__ W, int N,
            float* __restrict__ P, int Ktiles, int Kchunk) {
  __shared__ bf16_t As[256 * LDK];
  __shared__ bf16_t Bs[64 * LDK];
  int tid = threadIdx.x;
  int lane = tid & 63, wave = tid >> 6;
  int n0 = blockIdx.x * 64;
  int k0 = blockIdx.z * Kchunk;
  int bn = tid & 63, bkg = tid >> 6;   // B staging: n, k-group(8)
  int fm = lane & 15, kq = lane >> 4;  // fragment lane decode

  f32x4 acc[4][4];
#pragma unroll
  for (int i = 0; i < 4; ++i)
#pragma unroll
    for (int j = 0; j < 4; ++j) acc[i][j] = (f32x4)0.0f;

  for (int kt = 0; kt < Ktiles; ++kt) {
    int kb = k0 + kt * 32;
    // stage A: thread = row, 4 x 16B
    const bf16_t* Ar = A + (size_t)tid * lda + kb;
#pragma unroll
    for (int j = 0; j < 4; ++j) {
      bf16x8 v = *(const bf16x8*)(Ar + j * 8);
      *(bf16x8*)(&As[tid * LDK + j * 8]) = v;
    }
    // stage B transposed: Bs[n][k], fp32 -> bf16 during load
    {
      const float* Wp = W + (size_t)(kb + bkg * 8) * N + n0 + bn;
      bf16x8 bv;
#pragma unroll
      for (int j = 0; j < 8; ++j) bv[j] = (__bf16)Wp[(size_t)j * N];
      *(bf16x8*)(&Bs[bn * LDK + bkg * 8]) = bv;
    }
    __syncthreads();
    bf16x8 aF[4], bF[4];
#pragma unroll
    for (int i = 0; i < 4; ++i)
      aF[i] = *(const bf16x8*)(&As[(wave * 64 + i * 16 + fm) * LDK + kq * 8]);
#pragma unroll
    for (int j = 0; j < 4; ++j)
      bF[j] = *(const bf16x8*)(&Bs[(j * 16 + fm) * LDK + kq * 8]);
#pragma unroll
    for (int i = 0; i < 4; ++i)
#pragma unroll
      for (int j = 0; j < 4; ++j)
        acc[i][j] = __builtin_amdgcn_mfma_f32_16x16x32_bf16(aF[i], bF[j], acc[i][j], 0, 0, 0);
    __syncthreads();
  }
  // epilogue: C/D layout col=lane&15, row=(lane>>4)*4+reg  [m89-verified]
  float* Pp = P + (size_t)blockIdx.z * 256 * N + n0;
#pragma unroll
  for (int i = 0; i < 4; ++i) {
    int mrow = wave * 64 + i * 16 + kq * 4;
#pragma unroll
    for (int j = 0; j < 4; ++j)
#pragma unroll
      for (int r = 0; r < 4; ++r)
        Pp[(size_t)(mrow + r) * N + j * 16 + fm] = acc[i][j][r];
  }
}

// h = leaky(sum_s P1[s] + t*W1[1024,:] + b1), stored bf16
__global__ __launch_bounds__(256, 2)
void reduce1_k(const float* __restrict__ P1, const float* __restrict__ W1,
               const float* __restrict__ b1, const float* __restrict__ rt,
               bf16_t* __restrict__ h) {
  int e = (blockIdx.x * 256 + threadIdx.x) * 4;
  int b = e >> 11, n = e & 2047;
  float4 s = *(const float4*)(P1 + e);
#pragma unroll
  for (int sp = 1; sp < 8; ++sp) {
    float4 v = *(const float4*)(P1 + (size_t)sp * 524288 + e);
    s.x += v.x; s.y += v.y; s.z += v.z; s.w += v.w;
  }
  float tv = rt[b];
  float4 wl = *(const float4*)(W1 + 1024 * 2048 + n);
  float4 bb = *(const float4*)(b1 + n);
  s.x += tv * wl.x + bb.x;
  s.y += tv * wl.y + bb.y;
  s.z += tv * wl.z + bb.z;
  s.w += tv * wl.w + bb.w;
  bf16x4 o;
  o[0] = (__bf16)(s.x >= 0.f ? s.x : 0.01f * s.x);
  o[1] = (__bf16)(s.y >= 0.f ? s.y : 0.01f * s.y);
  o[2] = (__bf16)(s.z >= 0.f ? s.z : 0.01f * s.z);
  o[3] = (__bf16)(s.w >= 0.f ? s.w : 0.01f * s.w);
  *(bf16x4*)(h + e) = o;
}

// one thread per element; reduce GEMM2 partials, windowed erf bucket sum, weighted MSE
__global__ __launch_bounds__(256, 4)
void loss_k(const float* __restrict__ x, const float* __restrict__ noise,
            const float* __restrict__ P2, const float* __restrict__ b2,
            const float4* __restrict__ rc4, const float* __restrict__ rt,
            float* __restrict__ out) {
  int gid = blockIdx.x * 256 + threadIdx.x;  // 0..262143
  int b = gid >> 10, d = gid & 1023;
  float4 rc = rc4[b];
  float tv = rt[b];
  float om = rc.y, r = rc.z, w = rc.w;
  bool lowt = tv < 1e-10f;
  int base2 = b * 2048 + d;
  float me = b2[d], lg = b2[1024 + d];
#pragma unroll
  for (int sp = 0; sp < 8; ++sp) {
    me += P2[(size_t)sp * 524288 + base2];
    lg += P2[(size_t)sp * 524288 + base2 + 1024];
  }
  float xs = x[gid], ns = noise[gid];

  float mu_x = xs + om * ns - r * me;        // mu/gamma - r*mu_eps
  float sig = r * __expf(lg);
  if (lowt) { mu_x = 0.f; sig = 1.f; }
  float invs = 0.70710678118654752f / sig;   // 1/(sigma*sqrt(2))
  float a = invs * 0.015625f;                // z step per k
  float c0 = (1.f + mu_x) * invs;            // z_k = a*k - c0
  // window |z|<3.5 for the k=1..126 interior sum; saturated tails counted exactly
  float m64 = 64.f * (1.f + mu_x);
  float wdt = 316.78383797157331f * sig;     // 3.5/a = 224*sqrt(2)*sig
  float lo = m64 - wdt, hi = m64 + wdt;
  int klo = (lo < 1.f) ? 1 : ((lo > 126.f) ? 127 : (int)ceilf(lo));
  int khi = (hi < 1.f) ? 0 : ((hi > 126.f) ? 126 : (int)floorf(hi));
  float ss = (float)(126 - khi) - (float)(klo - 1);  // erf=+1 above window, -1 below
  for (int k = klo; k <= khi; ++k) ss += erf_f(fmaf(a, (float)k, -c0));
  // non-saturated right edge term at k=127 (kr_127 = 63/64 < 1, not clamped)
  float z127 = fmaf(a, 127.f, -c0);
  float pO = fmaf(0.48828125f, 1.f + erf_f(z127),      // (125/256)(1+erf(z127))
                  fmaf(-0.0078125f, ss, -0.984375f));  // -(1/128)ss - 126/128
  float df = xs - pO;
  float accv = w * df * df;
#pragma unroll
  for (int off = 32; off > 0; off >>= 1) accv += __shfl_down(accv, off, 64);
  __shared__ float red[4];
  if ((threadIdx.x & 63) == 0) red[threadIdx.x >> 6] = accv;
  __syncthreads();
  if (threadIdx.x == 0) {
    const float SCALE = 3.9120230054281461f / 262144.0f;  // -ln(0.02)/(B*D)
    atomicAdd(out, (red[0] + red[1] + red[2] + red[3]) * SCALE);
  }
}

extern "C" void kernel_launch(void* const* d_in, const int* in_sizes, int n_in,
                              void* d_out, int out_size, void* d_ws, size_t ws_size,
                              hipStream_t stream) {
  const float* x     = (const float*)d_in[0];
  const float* t     = (const float*)d_in[1];
  const float* noise = (const float*)d_in[2];
  const float* W1    = (const float*)d_in[3];
  const float* b1    = (const float*)d_in[4];
  const float* W2    = (const float*)d_in[5];
  const float* b2    = (const float*)d_in[6];
  float* out = (float*)d_out;

  // ws layout (needs ~33.6 MB)
  char* ws = (char*)d_ws;
  float4* rc4 = (float4*)ws;                           // 4 KB
  float*  rt  = (float*)(ws + 4096);                   // 1 KB
  bf16_t* A1  = (bf16_t*)(ws + 8192);                  // 512 KB
  bf16_t* h   = (bf16_t*)(ws + 8192 + 524288);         // 1 MB
  float*  P1  = (float*)(ws + 8192 + 524288 + 1048576);            // 16 MB
  float*  P2  = (float*)(ws + 8192 + 524288 + 1048576 + 16777216); // 16 MB

  hipMemsetAsync(d_out, 0, sizeof(float), stream);
  prep_k<<<256, 256, 0, stream>>>(x, noise, t, rc4, rt, A1);
  gemm_k<<<dim3(32, 1, 8), 256, 0, stream>>>(A1, 1024, W1, 2048, P1, 4, 128);
  reduce1_k<<<512, 256, 0, stream>>>(P1, W1, b1, rt, h);
  gemm_k<<<dim3(32, 1, 8), 256, 0, stream>>>(h, 2048, W2, 2048, P2, 8, 256);
  loss_k<<<1024, 256, 0, stream>>>(x, noise, P2, b2, rc4, rt, out);
}

// Round 6
// 129.323 us; speedup vs baseline: 1.3846x; 1.0207x over previous
//
#include <hip/hip_runtime.h>
#include <hip/hip_bf16.h>
#include <math.h>

// DiscretisedBNF loss, MI355X gfx950.
// Pipeline: prep(row consts + A1 bf16) -> GEMM1(splitK=8) -> reduce1(bias+t*W1row+leaky->h bf16)
//           -> GEMM2(splitK=8) -> loss (reduce partials + windowed erf-sum + weighted MSE).
// Abel summation (k=127 edge kept un-saturated):
//   pO = (125/256)(1+erf(z_127)) - 126/128 - (1/128) sum_{k=1..126} erf(z_k),
//   z_k = (k/64 - 1 - mu_x) / (sigma*sqrt(2)).
// R6: R4/R5 NaN root-caused — A-tile staging wrote only 16 of 32 k-elements per row
//     (shrunk the A loop when shrinking BN; As[16..31] was ws-poison -> NaN through MFMA).
//     Fix: stage 4 x bf16x8 per row. BN=32 (grid 512 = 2 blocks/CU) retained.

typedef __bf16 bf16_t;
typedef __bf16 bf16x8 __attribute__((ext_vector_type(8)));
typedef __bf16 bf16x4 __attribute__((ext_vector_type(4)));
typedef float  f32x4  __attribute__((ext_vector_type(4)));

#define LDK 40  // LDS row stride in bf16 (32 + 8 pad): 80B rows, 16B-aligned

// Abramowitz-Stegun 7.1.26, |abs err| <= 1.5e-7, branch-free full-range.
__device__ __forceinline__ float erf_f(float x) {
  float ax = __builtin_fabsf(x);
  float t = __builtin_amdgcn_rcpf(fmaf(0.3275911f, ax, 1.0f));
  float p = fmaf(fmaf(fmaf(fmaf(1.061405429f, t, -1.453152027f), t, 1.421413741f),
                      t, -0.284496736f), t, 0.254829592f);
  p *= t;
  float e = __expf(-ax * ax);
  float r = fmaf(-p, e, 1.0f);
  return __builtin_copysignf(r, x);
}

// block b handles row b (1024 elems, 256 thr x 4); also emits row constants.
__global__ __launch_bounds__(256, 2)
void prep_k(const float* __restrict__ x, const float* __restrict__ noise,
            const float* __restrict__ t, float4* __restrict__ rc4,
            bf16_t* __restrict__ A1) {
  int b = blockIdx.x;
  float tv = t[b];
  const float L2S = -5.6438561897747248f;  // log2(0.02)
  float p = exp2f(2.0f * tv * L2S);        // 1-gamma = 0.02^(2t)
  float gamma = 1.0f - p;
  if (threadIdx.x == 0) {
    float r = sqrtf(p / gamma);
    float w = 1.0f / p;                    // SIGMA1^(-2t)
    rc4[b] = make_float4(gamma, p, r, w);
  }
  int e = (b * 256 + threadIdx.x) * 4;
  float4 xv = *(const float4*)(x + e);
  float4 nv = *(const float4*)(noise + e);
  float g = gamma, gom = gamma * p;        // gamma, gamma*(1-gamma)
  bf16x4 o;
  o[0] = (__bf16)(g * xv.x + gom * nv.x);
  o[1] = (__bf16)(g * xv.y + gom * nv.y);
  o[2] = (__bf16)(g * xv.z + gom * nv.z);
  o[3] = (__bf16)(g * xv.w + gom * nv.w);
  *(bf16x4*)(A1 + e) = o;
}

// P[z] = A[256 x Kchunk, bf16] @ W[Kchunk x N, f32->bf16].
// BM=256, BN=32, BK=32. 4 waves, each 64(m)x32(n) = 4x2 frags of 16x16x32.
// Loop shape: stage -> barrier -> MFMA -> barrier (proven R3 structure).
__global__ __launch_bounds__(256, 2)
void gemm_k(const bf16_t* __restrict__ A, int lda,
            const float* __restrict__ W, int N,
            float* __restrict__ P, int Ktiles, int Kchunk) {
  __shared__ bf16_t As[256 * LDK];
  __shared__ bf16_t Bs[32 * LDK];
  int tid = threadIdx.x;
  int lane = tid & 63, wave = tid >> 6;
  int n0 = blockIdx.x * 32;
  int k0 = blockIdx.z * Kchunk;
  int bn = tid & 31, bkg = tid >> 5;   // B staging: n (0..31), k-group of 4 (0..7)
  int fm = lane & 15, kq = lane >> 4;  // fragment lane decode

  f32x4 acc[4][2];
#pragma unroll
  for (int i = 0; i < 4; ++i)
#pragma unroll
    for (int j = 0; j < 2; ++j) acc[i][j] = (f32x4)0.0f;

  for (int kt = 0; kt < Ktiles; ++kt) {
    int kb = k0 + kt * 32;
    // stage A: thread = row, FULL BK=32: 4 x 8 bf16 (R6 fix — was 2 x 8)
    const bf16_t* Ar = A + (size_t)tid * lda + kb;
#pragma unroll
    for (int j = 0; j < 4; ++j)
      *(bf16x8*)(&As[tid * LDK + j * 8]) = *(const bf16x8*)(Ar + j * 8);
    // stage B transposed: Bs[n][k], fp32 -> bf16 during load (4 k-values/thread)
    {
      const float* Wp = W + (size_t)(kb + bkg * 4) * N + n0 + bn;
      bf16x4 bv;
#pragma unroll
      for (int i = 0; i < 4; ++i) bv[i] = (__bf16)Wp[(size_t)i * N];
      *(bf16x4*)(&Bs[bn * LDK + bkg * 4]) = bv;
    }
    __syncthreads();
    bf16x8 aF[4], bF[2];
#pragma unroll
    for (int i = 0; i < 4; ++i)
      aF[i] = *(const bf16x8*)(&As[(wave * 64 + i * 16 + fm) * LDK + kq * 8]);
#pragma unroll
    for (int j = 0; j < 2; ++j)
      bF[j] = *(const bf16x8*)(&Bs[(j * 16 + fm) * LDK + kq * 8]);
#pragma unroll
    for (int i = 0; i < 4; ++i)
#pragma unroll
      for (int j = 0; j < 2; ++j)
        acc[i][j] = __builtin_amdgcn_mfma_f32_16x16x32_bf16(aF[i], bF[j], acc[i][j], 0, 0, 0);
    __syncthreads();
  }
  // epilogue: C/D layout col=lane&15, row=(lane>>4)*4+reg  [m89-verified]
  float* Pp = P + (size_t)blockIdx.z * 256 * N + n0;
#pragma unroll
  for (int i = 0; i < 4; ++i) {
    int mrow = wave * 64 + i * 16 + kq * 4;
#pragma unroll
    for (int j = 0; j < 2; ++j)
#pragma unroll
      for (int r = 0; r < 4; ++r)
        Pp[(size_t)(mrow + r) * N + j * 16 + fm] = acc[i][j][r];
  }
}

// h = leaky(sum_s P1[s] + t*W1[1024,:] + b1), stored bf16
__global__ __launch_bounds__(256, 2)
void reduce1_k(const float* __restrict__ P1, const float* __restrict__ W1,
               const float* __restrict__ b1, const float* __restrict__ t,
               bf16_t* __restrict__ h) {
  int e = (blockIdx.x * 256 + threadIdx.x) * 4;
  int b = e >> 11, n = e & 2047;
  float4 s = *(const float4*)(P1 + e);
#pragma unroll
  for (int sp = 1; sp < 8; ++sp) {
    float4 v = *(const float4*)(P1 + (size_t)sp * 524288 + e);
    s.x += v.x; s.y += v.y; s.z += v.z; s.w += v.w;
  }
  float tv = t[b];
  float4 wl = *(const float4*)(W1 + 1024 * 2048 + n);
  float4 bb = *(const float4*)(b1 + n);
  s.x += tv * wl.x + bb.x;
  s.y += tv * wl.y + bb.y;
  s.z += tv * wl.z + bb.z;
  s.w += tv * wl.w + bb.w;
  bf16x4 o;
  o[0] = (__bf16)(s.x >= 0.f ? s.x : 0.01f * s.x);
  o[1] = (__bf16)(s.y >= 0.f ? s.y : 0.01f * s.y);
  o[2] = (__bf16)(s.z >= 0.f ? s.z : 0.01f * s.z);
  o[3] = (__bf16)(s.w >= 0.f ? s.w : 0.01f * s.w);
  *(bf16x4*)(h + e) = o;
}

// one thread per element; reduce GEMM2 partials, windowed erf bucket sum, weighted MSE
__global__ __launch_bounds__(256, 4)
void loss_k(const float* __restrict__ x, const float* __restrict__ noise,
            const float* __restrict__ P2, const float* __restrict__ b2,
            const float4* __restrict__ rc4, const float* __restrict__ t,
            float* __restrict__ out) {
  int gid = blockIdx.x * 256 + threadIdx.x;  // 0..262143
  int b = gid >> 10, d = gid & 1023;
  float4 rc = rc4[b];
  float tv = t[b];
  float om = rc.y, r = rc.z, w = rc.w;
  bool lowt = tv < 1e-10f;
  int base2 = b * 2048 + d;
  float me = b2[d], lg = b2[1024 + d];
#pragma unroll
  for (int sp = 0; sp < 8; ++sp) {
    me += P2[(size_t)sp * 524288 + base2];
    lg += P2[(size_t)sp * 524288 + base2 + 1024];
  }
  float xs = x[gid], ns = noise[gid];

  float mu_x = xs + om * ns - r * me;        // mu/gamma - r*mu_eps
  float sig = r * __expf(lg);
  if (lowt) { mu_x = 0.f; sig = 1.f; }
  float invs = 0.70710678118654752f / sig;   // 1/(sigma*sqrt(2))
  float a = invs * 0.015625f;                // z step per k
  float c0 = (1.f + mu_x) * invs;            // z_k = a*k - c0
  // window |z|<3.5 for the k=1..126 interior sum; saturated tails counted exactly
  float m64 = 64.f * (1.f + mu_x);
  float wdt = 316.78383797157331f * sig;     // 3.5/a = 224*sqrt(2)*sig
  float lo = m64 - wdt, hi = m64 + wdt;
  int klo = (lo < 1.f) ? 1 : ((lo > 126.f) ? 127 : (int)ceilf(lo));
  int khi = (hi < 1.f) ? 0 : ((hi > 126.f) ? 126 : (int)floorf(hi));
  float ss = (float)(126 - khi) - (float)(klo - 1);  // erf=+1 above window, -1 below
  for (int k = klo; k <= khi; ++k) ss += erf_f(fmaf(a, (float)k, -c0));
  // non-saturated right edge term at k=127 (kr_127 = 63/64 < 1, not clamped)
  float z127 = fmaf(a, 127.f, -c0);
  float pO = fmaf(0.48828125f, 1.f + erf_f(z127),      // (125/256)(1+erf(z127))
                  fmaf(-0.0078125f, ss, -0.984375f));  // -(1/128)ss - 126/128
  float df = xs - pO;
  float accv = w * df * df;
#pragma unroll
  for (int off = 32; off > 0; off >>= 1) accv += __shfl_down(accv, off, 64);
  __shared__ float red[4];
  if ((threadIdx.x & 63) == 0) red[threadIdx.x >> 6] = accv;
  __syncthreads();
  if (threadIdx.x == 0) {
    const float SCALE = 3.9120230054281461f / 262144.0f;  // -ln(0.02)/(B*D)
    atomicAdd(out, (red[0] + red[1] + red[2] + red[3]) * SCALE);
  }
}

extern "C" void kernel_launch(void* const* d_in, const int* in_sizes, int n_in,
                              void* d_out, int out_size, void* d_ws, size_t ws_size,
                              hipStream_t stream) {
  const float* x     = (const float*)d_in[0];
  const float* t     = (const float*)d_in[1];
  const float* noise = (const float*)d_in[2];
  const float* W1    = (const float*)d_in[3];
  const float* b1    = (const float*)d_in[4];
  const float* W2    = (const float*)d_in[5];
  const float* b2    = (const float*)d_in[6];
  float* out = (float*)d_out;

  // ws layout (needs ~33.6 MB)
  char* ws = (char*)d_ws;
  float4* rc4 = (float4*)ws;                           // 4 KB
  bf16_t* A1  = (bf16_t*)(ws + 8192);                  // 512 KB
  bf16_t* h   = (bf16_t*)(ws + 8192 + 524288);         // 1 MB
  float*  P1  = (float*)(ws + 8192 + 524288 + 1048576);            // 16 MB
  float*  P2  = (float*)(ws + 8192 + 524288 + 1048576 + 16777216); // 16 MB

  hipMemsetAsync(d_out, 0, sizeof(float), stream);
  prep_k<<<256, 256, 0, stream>>>(x, noise, t, rc4, A1);
  gemm_k<<<dim3(64, 1, 8), 256, 0, stream>>>(A1, 1024, W1, 2048, P1, 4, 128);
  reduce1_k<<<512, 256, 0, stream>>>(P1, W1, b1, t, h);
  gemm_k<<<dim3(64, 1, 8), 256, 0, stream>>>(h, 2048, W2, 2048, P2, 8, 256);
  loss_k<<<1024, 256, 0, stream>>>(x, noise, P2, b2, rc4, t, out);
}

// Round 8
// 126.167 us; speedup vs baseline: 1.4193x; 1.0250x over previous
//
#include <hip/hip_runtime.h>
#include <hip/hip_bf16.h>
#include <math.h>

// DiscretisedBNF loss, MI355X gfx950.
// Pipeline: prep(row consts + A1 bf16) -> GEMM1(splitK=8) -> reduce1(bias+t*W1row+leaky->h bf16)
//           -> GEMM2(splitK=8) -> loss (reduce partials + ANALYTIC erf bucket sum + weighted MSE).
// Abel summation (k=127 edge kept un-saturated):
//   pO = (125/256)(1+erf(z_127)) - 126/128 - (1/128) sum_{k=1..126} erf(z_k),
//   z_k = (k/64 - 1 - mu_x) / (sigma*sqrt(2)).
// R8: interior sum replaced by Euler-Maclaurin midpoint integral (O(1) instead of O(126)):
//   sum_{klo..khi} erf(ak-c0) ~ (1/a)[G(zb)-G(za)] - (a/(12 sqrt(pi)))(e^{-zb^2}-e^{-za^2}),
//   G(z)=z erf(z)+e^{-z^2}/sqrt(pi); za,zb at half-offset edges. a>1 -> direct sum (<=7 terms).
// R7 cooperative mega-kernel was rejected at launch (stub-value output) — reverted to the
// proven R6 6-dispatch structure.

typedef __bf16 bf16_t;
typedef __bf16 bf16x8 __attribute__((ext_vector_type(8)));
typedef __bf16 bf16x4 __attribute__((ext_vector_type(4)));
typedef float  f32x4  __attribute__((ext_vector_type(4)));

#define LDK 40  // LDS row stride in bf16 (32 + 8 pad): 80B rows, 16B-aligned

// Abramowitz-Stegun 7.1.26, |abs err| <= 1.5e-7, branch-free full-range.
__device__ __forceinline__ float erf_f(float x) {
  float ax = __builtin_fabsf(x);
  float t = __builtin_amdgcn_rcpf(fmaf(0.3275911f, ax, 1.0f));
  float p = fmaf(fmaf(fmaf(fmaf(1.061405429f, t, -1.453152027f), t, 1.421413741f),
                      t, -0.284496736f), t, 0.254829592f);
  p *= t;
  float e = __expf(-ax * ax);
  float r = fmaf(-p, e, 1.0f);
  return __builtin_copysignf(r, x);
}

// block b handles row b (1024 elems, 256 thr x 4); also emits row constants.
__global__ __launch_bounds__(256, 2)
void prep_k(const float* __restrict__ x, const float* __restrict__ noise,
            const float* __restrict__ t, float4* __restrict__ rc4,
            bf16_t* __restrict__ A1) {
  int b = blockIdx.x;
  float tv = t[b];
  const float L2S = -5.6438561897747248f;  // log2(0.02)
  float p = exp2f(2.0f * tv * L2S);        // 1-gamma = 0.02^(2t)
  float gamma = 1.0f - p;
  if (threadIdx.x == 0) {
    float r = sqrtf(p / gamma);
    float w = 1.0f / p;                    // SIGMA1^(-2t)
    rc4[b] = make_float4(gamma, p, r, w);
  }
  int e = (b * 256 + threadIdx.x) * 4;
  float4 xv = *(const float4*)(x + e);
  float4 nv = *(const float4*)(noise + e);
  float g = gamma, gom = gamma * p;        // gamma, gamma*(1-gamma)
  bf16x4 o;
  o[0] = (__bf16)(g * xv.x + gom * nv.x);
  o[1] = (__bf16)(g * xv.y + gom * nv.y);
  o[2] = (__bf16)(g * xv.z + gom * nv.z);
  o[3] = (__bf16)(g * xv.w + gom * nv.w);
  *(bf16x4*)(A1 + e) = o;
}

// P[z] = A[256 x Kchunk, bf16] @ W[Kchunk x N, f32->bf16].
// BM=256, BN=32, BK=32. 4 waves, each 64(m)x32(n) = 4x2 frags of 16x16x32.
__global__ __launch_bounds__(256, 2)
void gemm_k(const bf16_t* __restrict__ A, int lda,
            const float* __restrict__ W, int N,
            float* __restrict__ P, int Ktiles, int Kchunk) {
  __shared__ bf16_t As[256 * LDK];
  __shared__ bf16_t Bs[32 * LDK];
  int tid = threadIdx.x;
  int lane = tid & 63, wave = tid >> 6;
  int n0 = blockIdx.x * 32;
  int k0 = blockIdx.z * Kchunk;
  int bn = tid & 31, bkg = tid >> 5;   // B staging: n (0..31), k-group of 4 (0..7)
  int fm = lane & 15, kq = lane >> 4;  // fragment lane decode

  f32x4 acc[4][2];
#pragma unroll
  for (int i = 0; i < 4; ++i)
#pragma unroll
    for (int j = 0; j < 2; ++j) acc[i][j] = (f32x4)0.0f;

  for (int kt = 0; kt < Ktiles; ++kt) {
    int kb = k0 + kt * 32;
    // stage A: thread = row, FULL BK=32: 4 x 8 bf16
    const bf16_t* Ar = A + (size_t)tid * lda + kb;
#pragma unroll
    for (int j = 0; j < 4; ++j)
      *(bf16x8*)(&As[tid * LDK + j * 8]) = *(const bf16x8*)(Ar + j * 8);
    // stage B transposed: Bs[n][k], fp32 -> bf16 during load (4 k-values/thread)
    {
      const float* Wp = W + (size_t)(kb + bkg * 4) * N + n0 + bn;
      bf16x4 bv;
#pragma unroll
      for (int i = 0; i < 4; ++i) bv[i] = (__bf16)Wp[(size_t)i * N];
      *(bf16x4*)(&Bs[bn * LDK + bkg * 4]) = bv;
    }
    __syncthreads();
    bf16x8 aF[4], bF[2];
#pragma unroll
    for (int i = 0; i < 4; ++i)
      aF[i] = *(const bf16x8*)(&As[(wave * 64 + i * 16 + fm) * LDK + kq * 8]);
#pragma unroll
    for (int j = 0; j < 2; ++j)
      bF[j] = *(const bf16x8*)(&Bs[(j * 16 + fm) * LDK + kq * 8]);
#pragma unroll
    for (int i = 0; i < 4; ++i)
#pragma unroll
      for (int j = 0; j < 2; ++j)
        acc[i][j] = __builtin_amdgcn_mfma_f32_16x16x32_bf16(aF[i], bF[j], acc[i][j], 0, 0, 0);
    __syncthreads();
  }
  // epilogue: C/D layout col=lane&15, row=(lane>>4)*4+reg  [m89-verified]
  float* Pp = P + (size_t)blockIdx.z * 256 * N + n0;
#pragma unroll
  for (int i = 0; i < 4; ++i) {
    int mrow = wave * 64 + i * 16 + kq * 4;
#pragma unroll
    for (int j = 0; j < 2; ++j)
#pragma unroll
      for (int r = 0; r < 4; ++r)
        Pp[(size_t)(mrow + r) * N + j * 16 + fm] = acc[i][j][r];
  }
}

// h = leaky(sum_s P1[s] + t*W1[1024,:] + b1), stored bf16
__global__ __launch_bounds__(256, 2)
void reduce1_k(const float* __restrict__ P1, const float* __restrict__ W1,
               const float* __restrict__ b1, const float* __restrict__ t,
               bf16_t* __restrict__ h) {
  int e = (blockIdx.x * 256 + threadIdx.x) * 4;
  int b = e >> 11, n = e & 2047;
  float4 s = *(const float4*)(P1 + e);
#pragma unroll
  for (int sp = 1; sp < 8; ++sp) {
    float4 v = *(const float4*)(P1 + (size_t)sp * 524288 + e);
    s.x += v.x; s.y += v.y; s.z += v.z; s.w += v.w;
  }
  float tv = t[b];
  float4 wl = *(const float4*)(W1 + 1024 * 2048 + n);
  float4 bb = *(const float4*)(b1 + n);
  s.x += tv * wl.x + bb.x;
  s.y += tv * wl.y + bb.y;
  s.z += tv * wl.z + bb.z;
  s.w += tv * wl.w + bb.w;
  bf16x4 o;
  o[0] = (__bf16)(s.x >= 0.f ? s.x : 0.01f * s.x);
  o[1] = (__bf16)(s.y >= 0.f ? s.y : 0.01f * s.y);
  o[2] = (__bf16)(s.z >= 0.f ? s.z : 0.01f * s.z);
  o[3] = (__bf16)(s.w >= 0.f ? s.w : 0.01f * s.w);
  *(bf16x4*)(h + e) = o;
}

// one thread per element; reduce GEMM2 partials, ANALYTIC erf bucket sum, weighted MSE
__global__ __launch_bounds__(256, 4)
void loss_k(const float* __restrict__ x, const float* __restrict__ noise,
            const float* __restrict__ P2, const float* __restrict__ b2,
            const float4* __restrict__ rc4, const float* __restrict__ t,
            float* __restrict__ out) {
  int gid = blockIdx.x * 256 + threadIdx.x;  // 0..262143
  int b = gid >> 10, d = gid & 1023;
  float4 rc = rc4[b];
  float tv = t[b];
  float om = rc.y, r = rc.z, w = rc.w;
  bool lowt = tv < 1e-10f;
  int base2 = b * 2048 + d;
  float me = b2[d], lg = b2[1024 + d];
#pragma unroll
  for (int sp = 0; sp < 8; ++sp) {
    me += P2[(size_t)sp * 524288 + base2];
    lg += P2[(size_t)sp * 524288 + base2 + 1024];
  }
  float xs = x[gid], ns = noise[gid];

  float mu_x = xs + om * ns - r * me;        // mu/gamma - r*mu_eps
  float sig = r * __expf(lg);
  if (lowt) { mu_x = 0.f; sig = 1.f; }
  float invs = 0.70710678118654752f / sig;   // 1/(sigma*sqrt(2))
  float a = invs * 0.015625f;                // z step per k
  float c0 = (1.f + mu_x) * invs;            // z_k = a*k - c0
  // window |z|<3.5 for the k=1..126 interior sum; saturated tails counted exactly
  float m64 = 64.f * (1.f + mu_x);
  float wdt = 316.78383797157331f * sig;     // 3.5/a = 224*sqrt(2)*sig
  float lo = m64 - wdt, hi = m64 + wdt;
  int klo = (lo < 1.f) ? 1 : ((lo > 126.f) ? 127 : (int)ceilf(lo));
  int khi = (hi < 1.f) ? 0 : ((hi > 126.f) ? 126 : (int)floorf(hi));
  float ss = (float)(126 - khi) - (float)(klo - 1);  // erf=+1 above window, -1 below
  if (khi >= klo) {
    if (a <= 1.0f) {
      // Euler-Maclaurin midpoint: sum ~ (1/a)[G(zb)-G(za)] - (a/(12 sqrt(pi)))(eb-ea)
      float za = fmaf(a, (float)klo - 0.5f, -c0);
      float zb = fmaf(a, (float)khi + 0.5f, -c0);
      const float ISP = 0.56418958354775628f;  // 1/sqrt(pi)
      float ea = __expf(-za * za), eb = __expf(-zb * zb);
      float Ga = fmaf(za, erf_f(za), ISP * ea); // G(z)=z*erf(z)+e^{-z^2}/sqrt(pi), G'=erf
      float Gb = fmaf(zb, erf_f(zb), ISP * eb);
      float S = (Gb - Ga) * __builtin_amdgcn_rcpf(a)
              - a * 0.047015889f * (eb - ea);   // 1/(12*sqrt(pi))
      ss += S;
    } else {
      // narrow window: <= ~7 direct terms
      for (int k = klo; k <= khi; ++k) ss += erf_f(fmaf(a, (float)k, -c0));
    }
  }
  // non-saturated right edge term at k=127 (kr_127 = 63/64 < 1, not clamped)
  float z127 = fmaf(a, 127.f, -c0);
  float pO = fmaf(0.48828125f, 1.f + erf_f(z127),      // (125/256)(1+erf(z127))
                  fmaf(-0.0078125f, ss, -0.984375f));  // -(1/128)ss - 126/128
  float df = xs - pO;
  float accv = w * df * df;
#pragma unroll
  for (int off = 32; off > 0; off >>= 1) accv += __shfl_down(accv, off, 64);
  __shared__ float red[4];
  if ((threadIdx.x & 63) == 0) red[threadIdx.x >> 6] = accv;
  __syncthreads();
  if (threadIdx.x == 0) {
    const float SCALE = 3.9120230054281461f / 262144.0f;  // -ln(0.02)/(B*D)
    atomicAdd(out, (red[0] + red[1] + red[2] + red[3]) * SCALE);
  }
}

extern "C" void kernel_launch(void* const* d_in, const int* in_sizes, int n_in,
                              void* d_out, int out_size, void* d_ws, size_t ws_size,
                              hipStream_t stream) {
  const float* x     = (const float*)d_in[0];
  const float* t     = (const float*)d_in[1];
  const float* noise = (const float*)d_in[2];
  const float* W1    = (const float*)d_in[3];
  const float* b1    = (const float*)d_in[4];
  const float* W2    = (const float*)d_in[5];
  const float* b2    = (const float*)d_in[6];
  float* out = (float*)d_out;

  // ws layout (needs ~33.6 MB)
  char* ws = (char*)d_ws;
  float4* rc4 = (float4*)ws;                           // 4 KB
  bf16_t* A1  = (bf16_t*)(ws + 8192);                  // 512 KB
  bf16_t* h   = (bf16_t*)(ws + 8192 + 524288);         // 1 MB
  float*  P1  = (float*)(ws + 8192 + 524288 + 1048576);            // 16 MB
  float*  P2  = (float*)(ws + 8192 + 524288 + 1048576 + 16777216); // 16 MB

  hipMemsetAsync(d_out, 0, sizeof(float), stream);
  prep_k<<<256, 256, 0, stream>>>(x, noise, t, rc4, A1);
  gemm_k<<<dim3(64, 1, 8), 256, 0, stream>>>(A1, 1024, W1, 2048, P1, 4, 128);
  reduce1_k<<<512, 256, 0, stream>>>(P1, W1, b1, t, h);
  gemm_k<<<dim3(64, 1, 8), 256, 0, stream>>>(h, 2048, W2, 2048, P2, 8, 256);
  loss_k<<<1024, 256, 0, stream>>>(x, noise, P2, b2, rc4, t, out);
}